// Round 1
// baseline (1537.693 us; speedup 1.0000x reference)
//
#include <hip/hip_runtime.h>
#include <hip/hip_bf16.h>

#define FDIM 128
#define TM 32
#define NRBF 20
#define PI_OVER_CUT 0.6283185307179586f  // pi / 5.0

// Per-node fused kernel: h = silu(s@W1+b1); s_out = h@W2+b2 (cols [0,128) and
// [256,384) only); filt = rbf@Wf+bf (same cols); A = filt_g*ccut*s_out_g,
// M = filt_m*ccut*s_out_m.  Block = 128 threads (thread = output column),
// TM=32 nodes per block so W1/W2 reads are amortized 32x.
__global__ __launch_bounds__(128) void node_kernel(
    const float* __restrict__ node_s, const float* __restrict__ edge_dis,
    const float* __restrict__ W1, const float* __restrict__ b1,
    const float* __restrict__ W2, const float* __restrict__ b2,
    const float* __restrict__ Wf, const float* __restrict__ bf,
    float* __restrict__ A, float* __restrict__ M, int N)
{
    __shared__ float sh_s[TM][FDIM];
    __shared__ float sh_h[TM][FDIM];
    __shared__ float sh_rbf[TM][NRBF];
    __shared__ float sh_ccut[TM];

    const int tid = threadIdx.x;
    const int n0 = blockIdx.x * TM;
    const int nvalid = min(TM, N - n0);

    // stage node_s tile (TM x 128 floats) via float4
    {
        const float4* g4 = (const float4*)(node_s + (size_t)n0 * FDIM);
        float4* s4 = (float4*)&sh_s[0][0];
        const int lim = nvalid * FDIM / 4;
        for (int i = tid; i < lim; i += 128) s4[i] = g4[i];
    }
    // rbf features: 32 nodes x 20 k = 640 values, 5 per thread
    {
        const int base = tid * 5;
        #pragma unroll
        for (int i = 0; i < 5; i++) {
            int idx = base + i;
            int m = idx / NRBF;
            int k = idx - m * NRBF;
            if (m < nvalid) {
                float dd = edge_dis[n0 + m];
                sh_rbf[m][k] = sinf((float)(k + 1) * PI_OVER_CUT * dd) / dd;
            }
        }
        if (tid < nvalid) {
            float dd = edge_dis[n0 + tid];
            sh_ccut[tid] = (dd <= 5.0f) ? 0.5f * (cosf(PI_OVER_CUT * dd) + 1.0f) : 0.0f;
        }
    }
    __syncthreads();

    float acc[TM];

    // GEMM1: h[m][tid] = silu(sum_k s[m][k] * W1[k][tid] + b1[tid])
    #pragma unroll
    for (int m = 0; m < TM; m++) acc[m] = 0.0f;
    for (int k = 0; k < FDIM; k++) {
        float w = W1[k * FDIM + tid];
        #pragma unroll
        for (int m = 0; m < TM; m++) acc[m] = fmaf(sh_s[m][k], w, acc[m]);
    }
    {
        float bb = b1[tid];
        #pragma unroll
        for (int m = 0; m < TM; m++) {
            float x = acc[m] + bb;
            sh_h[m][tid] = x / (1.0f + expf(-x));
        }
    }
    __syncthreads();

    // GEMM2 pass A: s_out cols [0,128)  -> gate A
    #pragma unroll
    for (int m = 0; m < TM; m++) acc[m] = 0.0f;
    for (int k = 0; k < FDIM; k++) {
        float w = W2[k * 384 + tid];
        #pragma unroll
        for (int m = 0; m < TM; m++) acc[m] = fmaf(sh_h[m][k], w, acc[m]);
    }
    {
        float wf[NRBF];
        #pragma unroll
        for (int k = 0; k < NRBF; k++) wf[k] = Wf[k * 384 + tid];
        float bft = bf[tid];
        float b2t = b2[tid];
        for (int m = 0; m < nvalid; m++) {
            float fg = bft;
            #pragma unroll
            for (int k = 0; k < NRBF; k++) fg = fmaf(sh_rbf[m][k], wf[k], fg);
            A[(size_t)(n0 + m) * FDIM + tid] = fg * sh_ccut[m] * (acc[m] + b2t);
        }
    }

    // GEMM2 pass B: s_out cols [256,384) -> scalar message M
    #pragma unroll
    for (int m = 0; m < TM; m++) acc[m] = 0.0f;
    for (int k = 0; k < FDIM; k++) {
        float w = W2[k * 384 + 256 + tid];
        #pragma unroll
        for (int m = 0; m < TM; m++) acc[m] = fmaf(sh_h[m][k], w, acc[m]);
    }
    {
        float wf[NRBF];
        #pragma unroll
        for (int k = 0; k < NRBF; k++) wf[k] = Wf[k * 384 + 256 + tid];
        float bft = bf[256 + tid];
        float b2t = b2[256 + tid];
        for (int m = 0; m < nvalid; m++) {
            float fm = bft;
            #pragma unroll
            for (int k = 0; k < NRBF; k++) fm = fmaf(sh_rbf[m][k], wf[k], fm);
            M[(size_t)(n0 + m) * FDIM + tid] = fm * sh_ccut[m] * (acc[m] + b2t);
        }
    }
}

// Edge scatter: 128 threads per edge (thread = channel), 2 edges per block.
__global__ __launch_bounds__(256) void edge_kernel(
    const int* __restrict__ edge, const float* __restrict__ A,
    const float* __restrict__ M, const float* __restrict__ node_vec,
    float* __restrict__ out_vec, float* __restrict__ out_s, int E)
{
    int e = blockIdx.x * 2 + (threadIdx.x >> 7);
    int c = threadIdx.x & 127;
    if (e >= E) return;
    int d = edge[2 * e];      // dst
    int s = edge[2 * e + 1];  // src

    float a = A[(size_t)s * FDIM + c];
    float m = M[(size_t)s * FDIM + c];
    const float* vp = node_vec + (size_t)s * 384 + 3 * c;
    float v0 = vp[0], v1 = vp[1], v2 = vp[2];

    atomicAdd(out_s + (size_t)d * FDIM + c, m);
    float* op = out_vec + (size_t)d * 384 + 3 * c;
    atomicAdd(op + 0, v0 * a);
    atomicAdd(op + 1, v1 * a);
    atomicAdd(op + 2, v2 * a);
}

extern "C" void kernel_launch(void* const* d_in, const int* in_sizes, int n_in,
                              void* d_out, int out_size, void* d_ws, size_t ws_size,
                              hipStream_t stream) {
    const float* node_s   = (const float*)d_in[0];
    const float* node_vec = (const float*)d_in[1];
    const int*   edge     = (const int*)d_in[2];
    // d_in[3] = edge_difference : unused by the reference
    const float* edge_dis = (const float*)d_in[4];
    const float* W1 = (const float*)d_in[5];
    const float* b1 = (const float*)d_in[6];
    const float* W2 = (const float*)d_in[7];
    const float* b2 = (const float*)d_in[8];
    const float* Wf = (const float*)d_in[9];
    const float* bf = (const float*)d_in[10];

    const int N = in_sizes[0] / FDIM;
    const int E = in_sizes[2] / 2;

    float* out_vec = (float*)d_out;              // N*128*3
    float* out_s   = out_vec + (size_t)N * 384;  // N*128
    float* A = (float*)d_ws;                     // N*128
    float* M = A + (size_t)N * FDIM;             // N*128

    // init outputs = inputs (then scatter-add on top)
    hipMemcpyAsync(out_vec, node_vec, (size_t)N * 384 * sizeof(float),
                   hipMemcpyDeviceToDevice, stream);
    hipMemcpyAsync(out_s, node_s, (size_t)N * FDIM * sizeof(float),
                   hipMemcpyDeviceToDevice, stream);

    node_kernel<<<(N + TM - 1) / TM, 128, 0, stream>>>(
        node_s, edge_dis, W1, b1, W2, b2, Wf, bf, A, M, N);

    edge_kernel<<<(E + 1) / 2, 256, 0, stream>>>(
        edge, A, M, node_vec, out_vec, out_s, E);
}

// Round 2
// 393.133 us; speedup vs baseline: 3.9114x; 3.9114x over previous
//
#include <hip/hip_runtime.h>
#include <hip/hip_bf16.h>

#define FDIM 128
#define TM 32
#define NRBF 20
#define PI_OVER_CUT 0.6283185307179586f  // pi / 5.0

// ---------------- per-node MLP/filter kernel (unchanged from R1) -----------
__global__ __launch_bounds__(128) void node_kernel(
    const float* __restrict__ node_s, const float* __restrict__ edge_dis,
    const float* __restrict__ W1, const float* __restrict__ b1,
    const float* __restrict__ W2, const float* __restrict__ b2,
    const float* __restrict__ Wf, const float* __restrict__ bf,
    float* __restrict__ A, float* __restrict__ M, int N)
{
    __shared__ float sh_s[TM][FDIM];
    __shared__ float sh_h[TM][FDIM];
    __shared__ float sh_rbf[TM][NRBF];
    __shared__ float sh_ccut[TM];

    const int tid = threadIdx.x;
    const int n0 = blockIdx.x * TM;
    const int nvalid = min(TM, N - n0);

    {
        const float4* g4 = (const float4*)(node_s + (size_t)n0 * FDIM);
        float4* s4 = (float4*)&sh_s[0][0];
        const int lim = nvalid * FDIM / 4;
        for (int i = tid; i < lim; i += 128) s4[i] = g4[i];
    }
    {
        const int base = tid * 5;
        #pragma unroll
        for (int i = 0; i < 5; i++) {
            int idx = base + i;
            int m = idx / NRBF;
            int k = idx - m * NRBF;
            if (m < nvalid) {
                float dd = edge_dis[n0 + m];
                sh_rbf[m][k] = sinf((float)(k + 1) * PI_OVER_CUT * dd) / dd;
            }
        }
        if (tid < nvalid) {
            float dd = edge_dis[n0 + tid];
            sh_ccut[tid] = (dd <= 5.0f) ? 0.5f * (cosf(PI_OVER_CUT * dd) + 1.0f) : 0.0f;
        }
    }
    __syncthreads();

    float acc[TM];

    // GEMM1 + silu
    #pragma unroll
    for (int m = 0; m < TM; m++) acc[m] = 0.0f;
    for (int k = 0; k < FDIM; k++) {
        float w = W1[k * FDIM + tid];
        #pragma unroll
        for (int m = 0; m < TM; m++) acc[m] = fmaf(sh_s[m][k], w, acc[m]);
    }
    {
        float bb = b1[tid];
        #pragma unroll
        for (int m = 0; m < TM; m++) {
            float x = acc[m] + bb;
            sh_h[m][tid] = x / (1.0f + expf(-x));
        }
    }
    __syncthreads();

    // GEMM2 cols [0,128) -> vector gate A
    #pragma unroll
    for (int m = 0; m < TM; m++) acc[m] = 0.0f;
    for (int k = 0; k < FDIM; k++) {
        float w = W2[k * 384 + tid];
        #pragma unroll
        for (int m = 0; m < TM; m++) acc[m] = fmaf(sh_h[m][k], w, acc[m]);
    }
    {
        float wf[NRBF];
        #pragma unroll
        for (int k = 0; k < NRBF; k++) wf[k] = Wf[k * 384 + tid];
        float bft = bf[tid];
        float b2t = b2[tid];
        for (int m = 0; m < nvalid; m++) {
            float fg = bft;
            #pragma unroll
            for (int k = 0; k < NRBF; k++) fg = fmaf(sh_rbf[m][k], wf[k], fg);
            A[(size_t)(n0 + m) * FDIM + tid] = fg * sh_ccut[m] * (acc[m] + b2t);
        }
    }

    // GEMM2 cols [256,384) -> scalar message M
    #pragma unroll
    for (int m = 0; m < TM; m++) acc[m] = 0.0f;
    for (int k = 0; k < FDIM; k++) {
        float w = W2[k * 384 + 256 + tid];
        #pragma unroll
        for (int m = 0; m < TM; m++) acc[m] = fmaf(sh_h[m][k], w, acc[m]);
    }
    {
        float wf[NRBF];
        #pragma unroll
        for (int k = 0; k < NRBF; k++) wf[k] = Wf[k * 384 + 256 + tid];
        float bft = bf[256 + tid];
        float b2t = b2[256 + tid];
        for (int m = 0; m < nvalid; m++) {
            float fm = bft;
            #pragma unroll
            for (int k = 0; k < NRBF; k++) fm = fmaf(sh_rbf[m][k], wf[k], fm);
            M[(size_t)(n0 + m) * FDIM + tid] = fm * sh_ccut[m] * (acc[m] + b2t);
        }
    }
}

// ---------------- CSR build ------------------------------------------------
__global__ __launch_bounds__(256) void hist_kernel(
    const int* __restrict__ edge, int* __restrict__ counts, int E)
{
    int i = blockIdx.x * 256 + threadIdx.x;
    if (i < E) atomicAdd(&counts[edge[2 * i]], 1);
}

// Single-block exclusive scan of `counts[0..N)` -> offsets[0..N], cursor copy.
__global__ __launch_bounds__(1024) void scan_kernel(
    const int* __restrict__ counts, int* __restrict__ offsets,
    int* __restrict__ cursor, int N)
{
    __shared__ int sh[1024];
    const int t = threadIdx.x;
    const int chunk = (N + 1023) / 1024;
    const int beg = t * chunk, end = min(beg + chunk, N);

    int local = 0;
    for (int i = beg; i < end; i++) local += counts[i];
    sh[t] = local;
    __syncthreads();
    for (int off = 1; off < 1024; off <<= 1) {
        int v = (t >= off) ? sh[t - off] : 0;
        __syncthreads();
        sh[t] += v;
        __syncthreads();
    }
    int ex = sh[t] - local;  // exclusive prefix of this chunk
    int run = ex;
    for (int i = beg; i < end; i++) {
        offsets[i] = run;
        cursor[i] = run;
        run += counts[i];
    }
    if (t == 1023) offsets[N] = sh[1023];
}

__global__ __launch_bounds__(256) void scatter_kernel(
    const int* __restrict__ edge, int* __restrict__ cursor,
    int* __restrict__ src_sorted, int E)
{
    int i = blockIdx.x * 256 + threadIdx.x;
    if (i >= E) return;
    int d = edge[2 * i];
    int s = edge[2 * i + 1];
    int pos = atomicAdd(&cursor[d], 1);
    src_sorted[pos] = s;
}

// ---------------- gather-accumulate: one dst per 128 threads ---------------
__global__ __launch_bounds__(256) void gather_kernel(
    const int* __restrict__ offsets, const int* __restrict__ src_sorted,
    const float* __restrict__ A, const float* __restrict__ M,
    const float* __restrict__ node_vec, const float* __restrict__ node_s,
    float* __restrict__ out_vec, float* __restrict__ out_s, int N)
{
    int d = blockIdx.x * 2 + (threadIdx.x >> 7);
    int c = threadIdx.x & 127;
    if (d >= N) return;

    int beg = offsets[d];
    int end = offsets[d + 1];

    float acc_s = 0.0f, a0 = 0.0f, a1 = 0.0f, a2 = 0.0f;

    int j = beg;
    for (; j + 1 < end; j += 2) {
        int s0 = src_sorted[j];
        int s1 = src_sorted[j + 1];
        float ga = A[(size_t)s0 * FDIM + c];
        float gb = A[(size_t)s1 * FDIM + c];
        float ma = M[(size_t)s0 * FDIM + c];
        float mb = M[(size_t)s1 * FDIM + c];
        const float* va = node_vec + (size_t)s0 * 384 + 3 * c;
        const float* vb = node_vec + (size_t)s1 * 384 + 3 * c;
        float va0 = va[0], va1 = va[1], va2 = va[2];
        float vb0 = vb[0], vb1 = vb[1], vb2 = vb[2];
        acc_s += ma + mb;
        a0 = fmaf(va0, ga, fmaf(vb0, gb, a0));
        a1 = fmaf(va1, ga, fmaf(vb1, gb, a1));
        a2 = fmaf(va2, ga, fmaf(vb2, gb, a2));
    }
    if (j < end) {
        int s0 = src_sorted[j];
        float ga = A[(size_t)s0 * FDIM + c];
        acc_s += M[(size_t)s0 * FDIM + c];
        const float* va = node_vec + (size_t)s0 * 384 + 3 * c;
        a0 = fmaf(va[0], ga, a0);
        a1 = fmaf(va[1], ga, a1);
        a2 = fmaf(va[2], ga, a2);
    }

    out_s[(size_t)d * FDIM + c] = node_s[(size_t)d * FDIM + c] + acc_s;
    const float* ip = node_vec + (size_t)d * 384 + 3 * c;
    float* op = out_vec + (size_t)d * 384 + 3 * c;
    op[0] = ip[0] + a0;
    op[1] = ip[1] + a1;
    op[2] = ip[2] + a2;
}

extern "C" void kernel_launch(void* const* d_in, const int* in_sizes, int n_in,
                              void* d_out, int out_size, void* d_ws, size_t ws_size,
                              hipStream_t stream) {
    const float* node_s   = (const float*)d_in[0];
    const float* node_vec = (const float*)d_in[1];
    const int*   edge     = (const int*)d_in[2];
    const float* edge_dis = (const float*)d_in[4];
    const float* W1 = (const float*)d_in[5];
    const float* b1 = (const float*)d_in[6];
    const float* W2 = (const float*)d_in[7];
    const float* b2 = (const float*)d_in[8];
    const float* Wf = (const float*)d_in[9];
    const float* bf = (const float*)d_in[10];

    const int N = in_sizes[0] / FDIM;
    const int E = in_sizes[2] / 2;

    float* out_vec = (float*)d_out;              // N*128*3
    float* out_s   = out_vec + (size_t)N * 384;  // N*128

    // workspace layout
    float* A = (float*)d_ws;                         // N*128 f32
    float* M = A + (size_t)N * FDIM;                 // N*128 f32
    int* counts     = (int*)(M + (size_t)N * FDIM);  // N
    int* offsets    = counts + N;                    // N+1
    int* cursor     = offsets + N + 1;               // N
    int* src_sorted = cursor + N;                    // E

    hipMemsetAsync(counts, 0, (size_t)N * sizeof(int), stream);

    node_kernel<<<(N + TM - 1) / TM, 128, 0, stream>>>(
        node_s, edge_dis, W1, b1, W2, b2, Wf, bf, A, M, N);

    hist_kernel<<<(E + 255) / 256, 256, 0, stream>>>(edge, counts, E);
    scan_kernel<<<1, 1024, 0, stream>>>(counts, offsets, cursor, N);
    scatter_kernel<<<(E + 255) / 256, 256, 0, stream>>>(edge, cursor, src_sorted, E);

    gather_kernel<<<(N + 1) / 2, 256, 0, stream>>>(
        offsets, src_sorted, A, M, node_vec, node_s, out_vec, out_s, N);
}

// Round 4
// 343.661 us; speedup vs baseline: 4.4744x; 1.1440x over previous
//
#include <hip/hip_runtime.h>
#include <hip/hip_bf16.h>

#define FDIM 128
#define TMB 16   // nodes per block
#define TMH 8    // nodes per half-block (128 threads)
#define NRBF 20
#define PI_OVER_CUT 0.6283185307179586f  // pi / 5.0

// Per-node fused kernel, v2.1: 256 threads = 2 half-blocks x (thread = out col),
// 16 nodes/block -> grid 1250 (~19 waves/CU). sh_s reused for h after GEMM1.
// k-loop steps by 4 with ds_read_b128 for the activation row.
// v2 bug fixed: sh_rbf has 320 entries > 256 threads -> strided fill.
__global__ __launch_bounds__(256) void node_kernel(
    const float* __restrict__ node_s, const float* __restrict__ edge_dis,
    const float* __restrict__ W1, const float* __restrict__ b1,
    const float* __restrict__ W2, const float* __restrict__ b2,
    const float* __restrict__ Wf, const float* __restrict__ bf,
    float* __restrict__ A, float* __restrict__ M, int N)
{
    __shared__ float sh_s[TMB][FDIM];   // node_s tile; overwritten with h
    __shared__ float sh_rbf[TMB][NRBF];
    __shared__ float sh_ccut[TMB];

    const int tid = threadIdx.x;
    const int g   = tid >> 7;     // 0/1: which half-block
    const int c   = tid & 127;    // output column
    const int n0  = blockIdx.x * TMB;
    const int m0  = g * TMH;

    // stage node_s tile (16x128 floats = 512 float4)
    {
        const float4* g4 = (const float4*)(node_s + (size_t)n0 * FDIM);
        float4* s4 = (float4*)&sh_s[0][0];
        #pragma unroll
        for (int i = tid; i < TMB * FDIM / 4; i += 256) s4[i] = g4[i];
    }
    // rbf: 16 nodes x 20 k = 320 entries > 256 threads -> strided
    for (int idx = tid; idx < TMB * NRBF; idx += 256) {
        int m = idx / NRBF, k = idx - m * NRBF;
        float dd = edge_dis[n0 + m];
        sh_rbf[m][k] = sinf((float)(k + 1) * PI_OVER_CUT * dd) / dd;
    }
    if (tid < TMB) {
        float dd = edge_dis[n0 + tid];
        sh_ccut[tid] = (dd <= 5.0f) ? 0.5f * (cosf(PI_OVER_CUT * dd) + 1.0f) : 0.0f;
    }
    __syncthreads();

    float acc[TMH];

    // ---- GEMM1: h = silu(s @ W1 + b1) ----
    #pragma unroll
    for (int m = 0; m < TMH; m++) acc[m] = 0.0f;
    for (int k = 0; k < FDIM; k += 4) {
        float w0 = W1[(k + 0) * FDIM + c];
        float w1 = W1[(k + 1) * FDIM + c];
        float w2 = W1[(k + 2) * FDIM + c];
        float w3 = W1[(k + 3) * FDIM + c];
        #pragma unroll
        for (int m = 0; m < TMH; m++) {
            float4 s4 = *(const float4*)&sh_s[m0 + m][k];
            acc[m] = fmaf(s4.x, w0, fmaf(s4.y, w1, fmaf(s4.z, w2, fmaf(s4.w, w3, acc[m]))));
        }
    }
    __syncthreads();   // all reads of sh_s done before overwrite
    {
        float bb = b1[c];
        #pragma unroll
        for (int m = 0; m < TMH; m++) {
            float x = acc[m] + bb;
            sh_s[m0 + m][c] = x / (1.0f + expf(-x));
        }
    }
    __syncthreads();

    // ---- GEMM2 pass A: cols [0,128) -> vector gate A ----
    #pragma unroll
    for (int m = 0; m < TMH; m++) acc[m] = 0.0f;
    for (int k = 0; k < FDIM; k += 4) {
        float w0 = W2[(k + 0) * 384 + c];
        float w1 = W2[(k + 1) * 384 + c];
        float w2 = W2[(k + 2) * 384 + c];
        float w3 = W2[(k + 3) * 384 + c];
        #pragma unroll
        for (int m = 0; m < TMH; m++) {
            float4 s4 = *(const float4*)&sh_s[m0 + m][k];
            acc[m] = fmaf(s4.x, w0, fmaf(s4.y, w1, fmaf(s4.z, w2, fmaf(s4.w, w3, acc[m]))));
        }
    }
    {
        float wf[NRBF];
        #pragma unroll
        for (int k = 0; k < NRBF; k++) wf[k] = Wf[k * 384 + c];
        float bft = bf[c];
        float b2t = b2[c];
        #pragma unroll
        for (int m = 0; m < TMH; m++) {
            float fg = bft;
            #pragma unroll
            for (int k = 0; k < NRBF; k++) fg = fmaf(sh_rbf[m0 + m][k], wf[k], fg);
            A[(size_t)(n0 + m0 + m) * FDIM + c] = fg * sh_ccut[m0 + m] * (acc[m] + b2t);
        }
    }

    // ---- GEMM2 pass B: cols [256,384) -> scalar message M ----
    #pragma unroll
    for (int m = 0; m < TMH; m++) acc[m] = 0.0f;
    for (int k = 0; k < FDIM; k += 4) {
        float w0 = W2[(k + 0) * 384 + 256 + c];
        float w1 = W2[(k + 1) * 384 + 256 + c];
        float w2 = W2[(k + 2) * 384 + 256 + c];
        float w3 = W2[(k + 3) * 384 + 256 + c];
        #pragma unroll
        for (int m = 0; m < TMH; m++) {
            float4 s4 = *(const float4*)&sh_s[m0 + m][k];
            acc[m] = fmaf(s4.x, w0, fmaf(s4.y, w1, fmaf(s4.z, w2, fmaf(s4.w, w3, acc[m]))));
        }
    }
    {
        float wf[NRBF];
        #pragma unroll
        for (int k = 0; k < NRBF; k++) wf[k] = Wf[k * 384 + 256 + c];
        float bft = bf[256 + c];
        float b2t = b2[256 + c];
        #pragma unroll
        for (int m = 0; m < TMH; m++) {
            float fm = bft;
            #pragma unroll
            for (int k = 0; k < NRBF; k++) fm = fmaf(sh_rbf[m0 + m][k], wf[k], fm);
            M[(size_t)(n0 + m0 + m) * FDIM + c] = fm * sh_ccut[m0 + m] * (acc[m] + b2t);
        }
    }
}

// ---------------- CSR build ------------------------------------------------
__global__ __launch_bounds__(256) void hist_kernel(
    const int* __restrict__ edge, int* __restrict__ counts, int E)
{
    int i = blockIdx.x * 256 + threadIdx.x;
    if (i < E) atomicAdd(&counts[edge[2 * i]], 1);
}

__global__ __launch_bounds__(1024) void scan_kernel(
    const int* __restrict__ counts, int* __restrict__ offsets,
    int* __restrict__ cursor, int N)
{
    __shared__ int sh[1024];
    const int t = threadIdx.x;
    const int chunk = (N + 1023) / 1024;
    const int beg = t * chunk, end = min(beg + chunk, N);

    int local = 0;
    for (int i = beg; i < end; i++) local += counts[i];
    sh[t] = local;
    __syncthreads();
    for (int off = 1; off < 1024; off <<= 1) {
        int v = (t >= off) ? sh[t - off] : 0;
        __syncthreads();
        sh[t] += v;
        __syncthreads();
    }
    int run = sh[t] - local;  // exclusive prefix of this chunk
    for (int i = beg; i < end; i++) {
        offsets[i] = run;
        cursor[i] = run;
        run += counts[i];
    }
    if (t == 1023) offsets[N] = sh[1023];
}

__global__ __launch_bounds__(256) void scatter_kernel(
    const int* __restrict__ edge, int* __restrict__ cursor,
    int* __restrict__ src_sorted, int E)
{
    int i = blockIdx.x * 256 + threadIdx.x;
    if (i >= E) return;
    int d = edge[2 * i];
    int s = edge[2 * i + 1];
    int pos = atomicAdd(&cursor[d], 1);
    src_sorted[pos] = s;
}

// ---------------- gather-accumulate: one dst per 128 threads ---------------
__global__ __launch_bounds__(256) void gather_kernel(
    const int* __restrict__ offsets, const int* __restrict__ src_sorted,
    const float* __restrict__ A, const float* __restrict__ M,
    const float* __restrict__ node_vec, const float* __restrict__ node_s,
    float* __restrict__ out_vec, float* __restrict__ out_s, int N)
{
    int d = blockIdx.x * 2 + (threadIdx.x >> 7);
    int c = threadIdx.x & 127;
    if (d >= N) return;

    int beg = offsets[d];
    int end = offsets[d + 1];

    float acc_s = 0.0f, a0 = 0.0f, a1 = 0.0f, a2 = 0.0f;

    int j = beg;
    for (; j + 1 < end; j += 2) {
        int s0 = src_sorted[j];
        int s1 = src_sorted[j + 1];
        float ga = A[(size_t)s0 * FDIM + c];
        float gb = A[(size_t)s1 * FDIM + c];
        float ma = M[(size_t)s0 * FDIM + c];
        float mb = M[(size_t)s1 * FDIM + c];
        const float* va = node_vec + (size_t)s0 * 384 + 3 * c;
        const float* vb = node_vec + (size_t)s1 * 384 + 3 * c;
        float va0 = va[0], va1 = va[1], va2 = va[2];
        float vb0 = vb[0], vb1 = vb[1], vb2 = vb[2];
        acc_s += ma + mb;
        a0 = fmaf(va0, ga, fmaf(vb0, gb, a0));
        a1 = fmaf(va1, ga, fmaf(vb1, gb, a1));
        a2 = fmaf(va2, ga, fmaf(vb2, gb, a2));
    }
    if (j < end) {
        int s0 = src_sorted[j];
        float ga = A[(size_t)s0 * FDIM + c];
        acc_s += M[(size_t)s0 * FDIM + c];
        const float* va = node_vec + (size_t)s0 * 384 + 3 * c;
        a0 = fmaf(va[0], ga, a0);
        a1 = fmaf(va[1], ga, a1);
        a2 = fmaf(va[2], ga, a2);
    }

    out_s[(size_t)d * FDIM + c] = node_s[(size_t)d * FDIM + c] + acc_s;
    const float* ip = node_vec + (size_t)d * 384 + 3 * c;
    float* op = out_vec + (size_t)d * 384 + 3 * c;
    op[0] = ip[0] + a0;
    op[1] = ip[1] + a1;
    op[2] = ip[2] + a2;
}

extern "C" void kernel_launch(void* const* d_in, const int* in_sizes, int n_in,
                              void* d_out, int out_size, void* d_ws, size_t ws_size,
                              hipStream_t stream) {
    const float* node_s   = (const float*)d_in[0];
    const float* node_vec = (const float*)d_in[1];
    const int*   edge     = (const int*)d_in[2];
    const float* edge_dis = (const float*)d_in[4];
    const float* W1 = (const float*)d_in[5];
    const float* b1 = (const float*)d_in[6];
    const float* W2 = (const float*)d_in[7];
    const float* b2 = (const float*)d_in[8];
    const float* Wf = (const float*)d_in[9];
    const float* bf = (const float*)d_in[10];

    const int N = in_sizes[0] / FDIM;
    const int E = in_sizes[2] / 2;

    float* out_vec = (float*)d_out;              // N*128*3
    float* out_s   = out_vec + (size_t)N * 384;  // N*128

    // workspace layout
    float* A = (float*)d_ws;                         // N*128 f32
    float* M = A + (size_t)N * FDIM;                 // N*128 f32
    int* counts     = (int*)(M + (size_t)N * FDIM);  // N
    int* offsets    = counts + N;                    // N+1
    int* cursor     = offsets + N + 1;               // N
    int* src_sorted = cursor + N;                    // E

    hipMemsetAsync(counts, 0, (size_t)N * sizeof(int), stream);

    node_kernel<<<(N + TMB - 1) / TMB, 256, 0, stream>>>(
        node_s, edge_dis, W1, b1, W2, b2, Wf, bf, A, M, N);

    hist_kernel<<<(E + 255) / 256, 256, 0, stream>>>(edge, counts, E);
    scan_kernel<<<1, 1024, 0, stream>>>(counts, offsets, cursor, N);
    scatter_kernel<<<(E + 255) / 256, 256, 0, stream>>>(edge, cursor, src_sorted, E);

    gather_kernel<<<(N + 1) / 2, 256, 0, stream>>>(
        offsets, src_sorted, A, M, node_vec, node_s, out_vec, out_s, N);
}